// Round 7
// baseline (484.134 us; speedup 1.0000x reference)
//
#include <hip/hip_runtime.h>
#include <stdint.h>

typedef float    f32x4  __attribute__((ext_vector_type(4)));
typedef __bf16   bf16x8 __attribute__((ext_vector_type(8)));
typedef unsigned int u32x4 __attribute__((ext_vector_type(4)));
typedef unsigned short ushort_t;

#define NB     65536
#define BM     128
#define NSTEPS 40

// ---- v7 dynamic LDS: 3-buffered A (3x16K @0) + 3-buffered B (3x24K @48K) = 120 KiB ----
#define LDS_A0 0
#define LDS_A1 16384
#define LDS_A2 32768
#define LDS_B0 49152
#define LDS_B1 73728
#define LDS_B2 98304
#define LDS_TOTAL 122880

// ws layout: [kt 0..39][g 0..2][n 0..255][128 B row], row = swizzled hi/lo image
#define WS_B_BYTES (40ull * 3ull * 256ull * 128ull)   // 3,932,160

union Frag8 { ushort_t u[8]; u32x4 q; bf16x8 v; };
struct FragSet { Frag8 ah0, al0, bh[3], bl[3]; };   // 32 VGPR

static __device__ __forceinline__ ushort_t bf16_rne(float x) {
  uint32_t u = __float_as_uint(x);
  u += 0x7FFFu + ((u >> 16) & 1u);
  return (ushort_t)(u >> 16);
}
static __device__ __forceinline__ float bf16_f(ushort_t h) {
  return __uint_as_float(((uint32_t)h) << 16);
}

typedef const __attribute__((address_space(1))) void gas_void;
typedef __attribute__((address_space(3))) void las_void;

static __device__ __forceinline__ void glds16(const void* g, void* l) {
  __builtin_amdgcn_global_load_lds((gas_void*)g, (las_void*)l, 16, 0, 0);
}

#define RD(p, off) (*(const u32x4*)((p) + (off)))

// ============================ prep: pack weights ============================
__global__ __launch_bounds__(256)
void prep_weights(const float* __restrict__ Wi, const float* __restrict__ Wo,
                  const float* __restrict__ Wu,
                  const float* __restrict__ Ui, const float* __restrict__ Uo,
                  const float* __restrict__ Uu,
                  char* __restrict__ wsB)
{
  const int idx = blockIdx.x * 256 + threadIdx.x;   // 122880 total
  const int qq = idx & 3;
  const int n  = (idx >> 2) & 255;
  const int t  = idx >> 10;        // kt*3 + g
  const int g  = t % 3;
  const int kt = t / 3;
  const float* Wg = (g == 0) ? Wi : (g == 1) ? Wo : Wu;
  const float* Ug = (g == 0) ? Ui : (g == 1) ? Uo : Uu;
  const int k0 = kt * 32 + qq * 8;
  const float* src;
  if (k0 < 256) {
    src = Wg + (size_t)n * 256 + k0;
  } else {
    const int kc = (k0 - 256) >> 8;
    const int m  = (k0 - 256) & 255;
    src = Ug + (size_t)kc * 65536 + (size_t)n * 256 + m;
  }
  f32x4 a = *(const f32x4*)src;
  f32x4 b = *(const f32x4*)(src + 4);
  Frag8 hi, lo;
  #pragma unroll
  for (int j = 0; j < 4; ++j) {
    ushort_t h0 = bf16_rne(a[j]);
    hi.u[j] = h0; lo.u[j] = bf16_rne(a[j] - bf16_f(h0));
    ushort_t h1 = bf16_rne(b[j]);
    hi.u[4 + j] = h1; lo.u[4 + j] = bf16_rne(b[j] - bf16_f(h1));
  }
  char* base = wsB + ((size_t)t * 256 + n) * 128;
  const int sw = n & 7;
  *(u32x4*)(base + ((qq ^ sw) << 4))       = hi.q;
  *(u32x4*)(base + (((qq | 4) ^ sw) << 4)) = lo.q;
}

// ========== v7: 3-buf LDS, frag-set prefetch one step ahead, 1 barrier/step ==========
__global__ __launch_bounds__(512, 2)
void treelstm_fused_v7(const float* __restrict__ inputs,
                       const float* __restrict__ children,
                       const char*  __restrict__ wsB,
                       const float* __restrict__ bi, const float* __restrict__ bo,
                       const float* __restrict__ bu,
                       float* __restrict__ out)
{
  extern __shared__ __align__(16) char lds[];

  const int tid = threadIdx.x;
  const int bid = blockIdx.x;
  // XCD swizzle over 2048 blocks
  const int wg     = (bid & 7) * 256 + (bid >> 3);
  const int strip  = wg >> 9;      // 0..3
  const int rowblk = wg & 511;
  const int b0 = rowblk * BM;
  const int n0 = strip * 64;

  const int rowA = tid >> 2;       // 0..127
  const int ca   = tid & 3;
  const int lane = tid & 63;
  const int wid  = tid >> 6;
  const int wr   = wid >> 2;       // 0..1
  const int wc   = wid & 3;        // 0..3
  const int lc   = lane & 15;
  const int qq   = lane >> 4;

  f32x4 acc0[3], acc1[3], acc2[3], acc3[3];   // per-rf named (rule #20)
  #pragma unroll
  for (int g = 0; g < 3; ++g) {
    acc0[g] = (f32x4){0.f,0.f,0.f,0.f}; acc1[g] = (f32x4){0.f,0.f,0.f,0.f};
    acc2[g] = (f32x4){0.f,0.f,0.f,0.f}; acc3[g] = (f32x4){0.f,0.f,0.f,0.f};
  }

  // ---- hoisted LDS pointers ----
  const int sw = lc & 7;
  const uint32_t hiOff = (uint32_t)((qq ^ sw) << 4);
  const uint32_t aOffH = (uint32_t)((wr * 64 + lc) * 128) + hiOff;
  const uint32_t bOffH = (uint32_t)((wc * 16 + lc) * 128) + hiOff;
  const char* pAh = lds + aOffH;            // + LDS_Ak + rf*2048 (imm)
  const char* pAl = lds + (aOffH ^ 64u);
  const char* pBh0 = lds + LDS_B0 + bOffH;  // + g*8192 (imm)
  const char* pBl0 = lds + LDS_B0 + (bOffH ^ 64u);
  const char* pBh1 = lds + LDS_B1 + bOffH;
  const char* pBl1 = lds + LDS_B1 + (bOffH ^ 64u);
  const char* pBh2 = lds + LDS_B2 + bOffH;
  const char* pBl2 = lds + LDS_B2 + (bOffH ^ 64u);

  const uint32_t wOffH = (uint32_t)(rowA * 128) + (uint32_t)(((ca ^ (rowA & 7))) << 4);
  char* wAh = lds + wOffH;                  // + LDS_Ak (imm)
  char* wAl = lds + (wOffH ^ 64u);

  auto aPtr = [&](int s) -> const float* {
    if (s < 8) return inputs + (size_t)(b0 + rowA) * 256 + s * 32 + ca * 8;
    const int ss = s - 8;
    const int kc = ss >> 3;
    const int m0 = (ss & 7) * 32;
    return children + ((size_t)kc * NB + (size_t)(b0 + rowA)) * 512 + m0 + ca * 8;
  };

  auto writeA = [&](int aStg, const f32x4& x, const f32x4& y) {
    Frag8 H, L;
    #pragma unroll
    for (int j = 0; j < 4; ++j) {
      __bf16 h0 = (__bf16)x[j];
      H.v[j] = h0; L.v[j] = (__bf16)(x[j] - (float)h0);
      __bf16 h1 = (__bf16)y[j];
      H.v[4 + j] = h1; L.v[4 + j] = (__bf16)(y[j] - (float)h1);
    }
    *(u32x4*)(wAh + aStg) = H.q;
    *(u32x4*)(wAl + aStg) = L.q;
  };

  auto stageB = [&](int s, int bufoff) {   // 3 glds per wave, 24 KB total
    #pragma unroll
    for (int j = 0; j < 3; ++j) {
      const int idx  = wid + j * 8;
      const int gate = idx >> 3;
      const int off  = (idx & 7) * 1024;
      glds16(wsB + (size_t)s * 98304 + (size_t)gate * 32768 + (size_t)n0 * 128 + off + lane * 16,
             lds + bufoff + gate * 8192 + off + lane * 16);
    }
  };

  auto gate3 = [&](f32x4 (&a)[3], const Frag8& fh, const Frag8& fl, const FragSet& S) {
    #pragma unroll
    for (int g = 0; g < 3; ++g) {
      a[g] = __builtin_amdgcn_mfma_f32_16x16x32_bf16(fh.v, S.bh[g].v, a[g], 0, 0, 0);
      a[g] = __builtin_amdgcn_mfma_f32_16x16x32_bf16(fl.v, S.bh[g].v, a[g], 0, 0, 0);
      a[g] = __builtin_amdgcn_mfma_f32_16x16x32_bf16(fh.v, S.bl[g].v, a[g], 0, 0, 0);
    }
  };

  auto prefetchSet = [&](FragSet& Q, int aNxt, const char* pbh, const char* pbl) {
    Q.ah0.q = RD(pAh, aNxt); Q.al0.q = RD(pAl, aNxt);
    #pragma unroll
    for (int g = 0; g < 3; ++g) {
      Q.bh[g].q = RD(pbh, g * 8192);
      Q.bl[g].q = RD(pbl, g * 8192);
    }
  };

  FragSet X, Y;
  f32x4 rx, ry;   // A(s+2) regs

  auto doStep = [&](int s, int aCur, int aNxt, int aStg, int bStg,
                    const char* pbhN, const char* pblN, FragSet& P, FragSet& Q) {
    // top: publish A(s+2), reload regs with A(s+3), stage B(s+2) — all vmem issued early
    writeA(aStg, rx, ry);
    { const int sl = (s + 3 <= NSTEPS - 1) ? s + 3 : NSTEPS - 1;
      const float* p = aPtr(sl);
      rx = *(const f32x4*)p; ry = *(const f32x4*)(p + 4); }
    stageB(s + 2, bStg);
    // JIT A-frags for this step (rf 1..3)
    Frag8 a1h, a1l, a2h, a2l, a3h, a3l;
    a1h.q = RD(pAh, aCur + 2048); a1l.q = RD(pAl, aCur + 2048);
    a2h.q = RD(pAh, aCur + 4096); a2l.q = RD(pAl, aCur + 4096);
    a3h.q = RD(pAh, aCur + 6144); a3l.q = RD(pAl, aCur + 6144);
    // prefetch next step's set
    prefetchSet(Q, aNxt, pbhN, pblN);
    // MFMA wall: rf0 is fully register-resident -> issues at cycle ~0
    gate3(acc0, P.ah0, P.al0, P);
    gate3(acc1, a1h, a1l, P);
    gate3(acc2, a2h, a2l, P);
    gate3(acc3, a3h, a3l, P);
    // single per-step sync; all vmem issued ~full step before -> drain free
    asm volatile("s_waitcnt vmcnt(0) lgkmcnt(0)\n\ts_barrier" ::: "memory");
    __builtin_amdgcn_sched_barrier(0);
  };

  // ---- prologue: fill A0,A1,B0,B1; rx=A(2); X = frags(0) ----
  {
    f32x4 t0x, t0y, t1x, t1y;
    { const float* p = aPtr(0); t0x = *(const f32x4*)p; t0y = *(const f32x4*)(p + 4); }
    { const float* p = aPtr(1); t1x = *(const f32x4*)p; t1y = *(const f32x4*)(p + 4); }
    stageB(0, LDS_B0);
    stageB(1, LDS_B1);
    { const float* p = aPtr(2); rx = *(const f32x4*)p; ry = *(const f32x4*)(p + 4); }
    writeA(LDS_A0, t0x, t0y);
    writeA(LDS_A1, t1x, t1y);
    asm volatile("s_waitcnt vmcnt(2) lgkmcnt(0)\n\ts_barrier" ::: "memory");
    __builtin_amdgcn_sched_barrier(0);
    prefetchSet(X, LDS_A0, pBh0, pBl0);
  }

  // ---- main loop: s = 0..35 (period-6 static buf/parity pattern) ----
  #pragma unroll 1
  for (int t = 0; t < 6; ++t) {
    const int s = 6 * t;
    doStep(s,     LDS_A0, LDS_A1, LDS_A2, LDS_B2, pBh1, pBl1, X, Y);
    doStep(s + 1, LDS_A1, LDS_A2, LDS_A0, LDS_B0, pBh2, pBl2, Y, X);
    doStep(s + 2, LDS_A2, LDS_A0, LDS_A1, LDS_B1, pBh0, pBl0, X, Y);
    doStep(s + 3, LDS_A0, LDS_A1, LDS_A2, LDS_B2, pBh1, pBl1, Y, X);
    doStep(s + 4, LDS_A1, LDS_A2, LDS_A0, LDS_B0, pBh2, pBl2, X, Y);
    doStep(s + 5, LDS_A2, LDS_A0, LDS_A1, LDS_B1, pBh0, pBl0, Y, X);
  }

  // ---- tail: s = 36, 37 still full pipeline (loads clamp); 38, 39 drain ----
  doStep(36, LDS_A0, LDS_A1, LDS_A2, LDS_B2, pBh1, pBl1, X, Y);
  doStep(37, LDS_A1, LDS_A2, LDS_A0, LDS_B0, pBh2, pBl2, Y, X);
  {
    // s=38: no staging; CUR=A2, NXT=buf0
    Frag8 a1h, a1l, a2h, a2l, a3h, a3l;
    a1h.q = RD(pAh, LDS_A2 + 2048); a1l.q = RD(pAl, LDS_A2 + 2048);
    a2h.q = RD(pAh, LDS_A2 + 4096); a2l.q = RD(pAl, LDS_A2 + 4096);
    a3h.q = RD(pAh, LDS_A2 + 6144); a3l.q = RD(pAl, LDS_A2 + 6144);
    prefetchSet(Y, LDS_A0, pBh0, pBl0);
    gate3(acc0, X.ah0, X.al0, X);
    gate3(acc1, a1h, a1l, X);
    gate3(acc2, a2h, a2l, X);
    gate3(acc3, a3h, a3l, X);
  }
  {
    // s=39: CUR=buf0
    Frag8 a1h, a1l, a2h, a2l, a3h, a3l;
    a1h.q = RD(pAh, LDS_A0 + 2048); a1l.q = RD(pAl, LDS_A0 + 2048);
    a2h.q = RD(pAh, LDS_A0 + 4096); a2l.q = RD(pAl, LDS_A0 + 4096);
    a3h.q = RD(pAh, LDS_A0 + 6144); a3l.q = RD(pAl, LDS_A0 + 6144);
    gate3(acc0, Y.ah0, Y.al0, Y);
    gate3(acc1, a1h, a1l, Y);
    gate3(acc2, a2h, a2l, Y);
    gate3(acc3, a3h, a3l, Y);
  }

  // ---- epilogue ----
  {
    const int n = n0 + wc * 16 + lc;
    const float bin = bi[n], bon = bo[n], bun = bu[n];
    auto epi = [&](const f32x4 (&a)[3], int rf) {
      const int brow = b0 + wr * 64 + rf * 16 + qq * 4;
      #pragma unroll
      for (int r = 0; r < 4; ++r) {
        const float iv = a[0][r] + bin;
        const float ov = a[1][r] + bon;
        const float uv = a[2][r] + bun;
        const float tu = 1.f - 2.f / (1.f + __expf(2.f * uv));
        const float si = 1.f / (1.f + __expf(-iv));
        const float cv = si * tu;
        const float so = 1.f / (1.f + __expf(-ov));
        const float tc = 1.f - 2.f / (1.f + __expf(2.f * cv));
        const float hv = so * tc;
        const size_t base = (size_t)(brow + r) * 512 + (size_t)n;
        out[base]       = hv;
        out[base + 256] = cv;
      }
    };
    epi(acc0, 0); epi(acc1, 1); epi(acc2, 2); epi(acc3, 3);
  }
}

// ================= v1 fallback (ws too small) =================
#define A_HI 0
#define A_LO 8192
#define B_HI 16384
#define B_LO 40960

__global__ __launch_bounds__(512, 2)
void treelstm_fused_v1(const float* __restrict__ inputs,
                       const float* __restrict__ children,
                       const float* __restrict__ Wi, const float* __restrict__ bi,
                       const float* __restrict__ Wo, const float* __restrict__ bo,
                       const float* __restrict__ Wu, const float* __restrict__ bu,
                       const float* __restrict__ Ui, const float* __restrict__ Uo,
                       const float* __restrict__ Uu,
                       float* __restrict__ out)
{
  __shared__ u32x4 lds_u4[4096];
  char* lds = (char*)lds_u4;
  const int tid = threadIdx.x;
  const int bid = blockIdx.x;
  const int wg     = (bid & 7) * 128 + (bid >> 3);
  const int strip  = wg >> 9;
  const int rowblk = wg & 511;
  const int b0 = rowblk * BM;
  const int n0 = strip * 128;
  const int rowA = tid >> 2;
  const int koff = (tid & 3) * 8;
  const float* Wg[3] = {Wi, Wo, Wu};
  const float* Ug[3] = {Ui, Uo, Uu};
  const int lane = tid & 63;
  const int wid  = tid >> 6;
  const int wr   = wid >> 2;
  const int wc   = wid & 3;
  const int lc   = lane & 15;
  const int qq   = lane >> 4;

  f32x4 acc[4][2][3];
  #pragma unroll
  for (int a = 0; a < 4; ++a)
    #pragma unroll
    for (int b = 0; b < 2; ++b)
      #pragma unroll
      for (int g = 0; g < 3; ++g)
        acc[a][b][g] = (f32x4){0.f, 0.f, 0.f, 0.f};

  float va[8];
  float vb[3][8];

  auto loadStep = [&](int s) {
    const int k0 = s * 32;
    const float* pa;
    if (s < 8) pa = inputs + (size_t)(b0 + rowA) * 256 + (k0 + koff);
    else {
      const int kc = (s - 8) >> 3;
      const int m0 = ((s - 8) & 7) * 32;
      pa = children + ((size_t)kc * NB + (size_t)(b0 + rowA)) * 512 + (m0 + koff);
    }
    f32x4 t0 = *(const f32x4*)pa;
    f32x4 t1 = *(const f32x4*)(pa + 4);
    #pragma unroll
    for (int j = 0; j < 4; ++j) { va[j] = t0[j]; va[4 + j] = t1[j]; }
    #pragma unroll
    for (int g = 0; g < 3; ++g) {
      const float* pb;
      if (s < 8) pb = Wg[g] + (size_t)(n0 + rowA) * 256 + (k0 + koff);
      else {
        const int kc = (s - 8) >> 3;
        const int m0 = ((s - 8) & 7) * 32;
        pb = Ug[g] + (size_t)kc * 65536 + (size_t)(n0 + rowA) * 256 + (m0 + koff);
      }
      f32x4 u0 = *(const f32x4*)pb;
      f32x4 u1 = *(const f32x4*)(pb + 4);
      #pragma unroll
      for (int j = 0; j < 4; ++j) { vb[g][j] = u0[j]; vb[g][4 + j] = u1[j]; }
    }
  };

  auto storeStep = [&]() {
    Frag8 h, l;
    #pragma unroll
    for (int j = 0; j < 8; ++j) {
      ushort_t hb = bf16_rne(va[j]);
      h.u[j] = hb;
      l.u[j] = bf16_rne(va[j] - bf16_f(hb));
    }
    *(u32x4*)(lds + A_HI + rowA * 64 + koff * 2) = h.q;
    *(u32x4*)(lds + A_LO + rowA * 64 + koff * 2) = l.q;
    #pragma unroll
    for (int g = 0; g < 3; ++g) {
      Frag8 hg, lg;
      #pragma unroll
      for (int j = 0; j < 8; ++j) {
        ushort_t hb = bf16_rne(vb[g][j]);
        hg.u[j] = hb;
        lg.u[j] = bf16_rne(vb[g][j] - bf16_f(hb));
      }
      *(u32x4*)(lds + B_HI + (g * 128 + rowA) * 64 + koff * 2) = hg.q;
      *(u32x4*)(lds + B_LO + (g * 128 + rowA) * 64 + koff * 2) = lg.q;
    }
  };

  auto computeStep = [&]() {
    Frag8 ah[4], al[4];
    #pragma unroll
    for (int rf = 0; rf < 4; ++rf) {
      const int row = wr * 64 + rf * 16 + lc;
      ah[rf].q = *(const u32x4*)(lds + A_HI + row * 64 + qq * 16);
      al[rf].q = *(const u32x4*)(lds + A_LO + row * 64 + qq * 16);
    }
    #pragma unroll
    for (int g = 0; g < 3; ++g) {
      #pragma unroll
      for (int cf = 0; cf < 2; ++cf) {
        const int col = wc * 32 + cf * 16 + lc;
        Frag8 bh, bl;
        bh.q = *(const u32x4*)(lds + B_HI + (g * 128 + col) * 64 + qq * 16);
        bl.q = *(const u32x4*)(lds + B_LO + (g * 128 + col) * 64 + qq * 16);
        #pragma unroll
        for (int rf = 0; rf < 4; ++rf) {
          acc[rf][cf][g] = __builtin_amdgcn_mfma_f32_16x16x32_bf16(ah[rf].v, bh.v, acc[rf][cf][g], 0, 0, 0);
          acc[rf][cf][g] = __builtin_amdgcn_mfma_f32_16x16x32_bf16(al[rf].v, bh.v, acc[rf][cf][g], 0, 0, 0);
          acc[rf][cf][g] = __builtin_amdgcn_mfma_f32_16x16x32_bf16(ah[rf].v, bl.v, acc[rf][cf][g], 0, 0, 0);
        }
      }
    }
  };

  loadStep(0);
  #pragma unroll 1
  for (int s = 0; s < NSTEPS; ++s) {
    if (s) __syncthreads();
    storeStep();
    __syncthreads();
    if (s + 1 < NSTEPS) loadStep(s + 1);
    computeStep();
  }

  #pragma unroll
  for (int cf = 0; cf < 2; ++cf) {
    const int n = n0 + wc * 32 + cf * 16 + lc;
    const float bin = bi[n], bon = bo[n], bun = bu[n];
    #pragma unroll
    for (int rf = 0; rf < 4; ++rf) {
      const int brow = b0 + wr * 64 + rf * 16 + qq * 4;
      #pragma unroll
      for (int r = 0; r < 4; ++r) {
        const float iv = acc[rf][cf][0][r] + bin;
        const float ov = acc[rf][cf][1][r] + bon;
        const float uv = acc[rf][cf][2][r] + bun;
        const float tu = 1.f - 2.f / (1.f + __expf(2.f * uv));
        const float si = 1.f / (1.f + __expf(-iv));
        const float cv = si * tu;
        const float so = 1.f / (1.f + __expf(-ov));
        const float tc = 1.f - 2.f / (1.f + __expf(2.f * cv));
        const float hv = so * tc;
        const size_t base = (size_t)(brow + r) * 512 + (size_t)n;
        out[base]       = hv;
        out[base + 256] = cv;
      }
    }
  }
}

extern "C" void kernel_launch(void* const* d_in, const int* in_sizes, int n_in,
                              void* d_out, int out_size, void* d_ws, size_t ws_size,
                              hipStream_t stream) {
  const float* inputs   = (const float*)d_in[0];
  const float* children = (const float*)d_in[1];
  const float* Wi = (const float*)d_in[3];
  const float* bi = (const float*)d_in[4];
  const float* Wo = (const float*)d_in[5];
  const float* bo = (const float*)d_in[6];
  const float* Wu = (const float*)d_in[7];
  const float* bu = (const float*)d_in[8];
  const float* Ui = (const float*)d_in[11];
  const float* Uo = (const float*)d_in[12];
  const float* Uu = (const float*)d_in[13];
  float* out = (float*)d_out;

  if (ws_size >= WS_B_BYTES) {
    char* wsB = (char*)d_ws;
    (void)hipFuncSetAttribute((const void*)treelstm_fused_v7,
                              hipFuncAttributeMaxDynamicSharedMemorySize, LDS_TOTAL);
    hipLaunchKernelGGL(prep_weights, dim3(480), dim3(256), 0, stream,
                       Wi, Wo, Wu, Ui, Uo, Uu, wsB);
    hipLaunchKernelGGL(treelstm_fused_v7, dim3(2048), dim3(512), LDS_TOTAL, stream,
                       inputs, children, wsB, bi, bo, bu, out);
  } else {
    hipLaunchKernelGGL(treelstm_fused_v1, dim3(1024), dim3(512), 0, stream,
                       inputs, children, Wi, bi, Wo, bo, Wu, bu, Ui, Uo, Uu, out);
  }
}

// Round 9
// 453.403 us; speedup vs baseline: 1.0678x; 1.0678x over previous
//
#include <hip/hip_runtime.h>
#include <stdint.h>

typedef float    f32x4  __attribute__((ext_vector_type(4)));
typedef float    f32x16 __attribute__((ext_vector_type(16)));
typedef __bf16   bf16x8 __attribute__((ext_vector_type(8)));
typedef unsigned int u32x4 __attribute__((ext_vector_type(4)));
typedef unsigned short ushort_t;

#define NB     65536
#define BM     128
#define NSTEPS 40

// ---- dynamic LDS (bytes): A dbuf 2x16K, B dbuf 2x24K = 80 KiB -> 2 blocks/CU ----
#define LDS_A0 0
#define LDS_A1 16384
#define LDS_B0 32768
#define LDS_B1 57344
#define LDS_TOTAL 81920

// ws layout: [kt 0..39][g 0..2][n 0..255][128 B row], row = swizzled hi/lo image
#define WS_B_BYTES (40ull * 3ull * 256ull * 128ull)   // 3,932,160

union Frag8 { ushort_t u[8]; u32x4 q; bf16x8 v; };

static __device__ __forceinline__ ushort_t bf16_rne(float x) {
  uint32_t u = __float_as_uint(x);
  u += 0x7FFFu + ((u >> 16) & 1u);
  return (ushort_t)(u >> 16);
}
static __device__ __forceinline__ float bf16_f(ushort_t h) {
  return __uint_as_float(((uint32_t)h) << 16);
}

typedef const __attribute__((address_space(1))) void gas_void;
typedef __attribute__((address_space(3))) void las_void;

static __device__ __forceinline__ void glds16(const void* g, void* l) {
  __builtin_amdgcn_global_load_lds((gas_void*)g, (las_void*)l, 16, 0, 0);
}

#define RD(p, off) (*(const u32x4*)((p) + (off)))

// ============================ prep: pack weights (unchanged image) ============================
__global__ __launch_bounds__(256)
void prep_weights(const float* __restrict__ Wi, const float* __restrict__ Wo,
                  const float* __restrict__ Wu,
                  const float* __restrict__ Ui, const float* __restrict__ Uo,
                  const float* __restrict__ Uu,
                  char* __restrict__ wsB)
{
  const int idx = blockIdx.x * 256 + threadIdx.x;   // 122880 total
  const int qq = idx & 3;
  const int n  = (idx >> 2) & 255;
  const int t  = idx >> 10;        // kt*3 + g
  const int g  = t % 3;
  const int kt = t / 3;
  const float* Wg = (g == 0) ? Wi : (g == 1) ? Wo : Wu;
  const float* Ug = (g == 0) ? Ui : (g == 1) ? Uo : Uu;
  const int k0 = kt * 32 + qq * 8;
  const float* src;
  if (k0 < 256) {
    src = Wg + (size_t)n * 256 + k0;
  } else {
    const int kc = (k0 - 256) >> 8;
    const int m  = (k0 - 256) & 255;
    src = Ug + (size_t)kc * 65536 + (size_t)n * 256 + m;
  }
  f32x4 a = *(const f32x4*)src;
  f32x4 b = *(const f32x4*)(src + 4);
  Frag8 hi, lo;
  #pragma unroll
  for (int j = 0; j < 4; ++j) {
    ushort_t h0 = bf16_rne(a[j]);
    hi.u[j] = h0; lo.u[j] = bf16_rne(a[j] - bf16_f(h0));
    ushort_t h1 = bf16_rne(b[j]);
    hi.u[4 + j] = h1; lo.u[4 + j] = bf16_rne(b[j] - bf16_f(h1));
  }
  char* base = wsB + ((size_t)t * 256 + n) * 128;
  const int sw = n & 7;
  *(u32x4*)(base + ((qq ^ sw) << 4))       = hi.q;
  *(u32x4*)(base + (((qq | 4) ^ sw) << 4)) = lo.q;
}

// ====== v9: 32x32x16 MFMA on the v6 structure (2 blk/CU, order-proof vmcnt(0) sync) ======
__global__ __launch_bounds__(512, 4)
void treelstm_fused_v9(const float* __restrict__ inputs,
                       const float* __restrict__ children,
                       const char*  __restrict__ wsB,
                       const float* __restrict__ bi, const float* __restrict__ bo,
                       const float* __restrict__ bu,
                       float* __restrict__ out)
{
  extern __shared__ __align__(16) char lds[];

  const int tid = threadIdx.x;
  const int bid = blockIdx.x;
  // XCD swizzle over 2048 blocks
  const int wg     = (bid & 7) * 256 + (bid >> 3);
  const int strip  = wg >> 9;      // 0..3
  const int rowblk = wg & 511;
  const int b0 = rowblk * BM;
  const int n0 = strip * 64;

  const int rowA = tid >> 2;       // 0..127  (staging row)
  const int ca   = tid & 3;        // staging k-chunk
  const int lane = tid & 63;
  const int wid  = tid >> 6;       // 0..7
  const int wr2  = wid >> 1;       // 0..3  (32-row slab)
  const int wc2  = wid & 1;        // 0..1  (32-col slab per gate)
  const int l31  = lane & 31;
  const int lh   = lane >> 5;      // k-half selector

  f32x16 acc[3];
  #pragma unroll
  for (int g = 0; g < 3; ++g)
    #pragma unroll
    for (int r = 0; r < 16; ++r)
      acc[g][r] = 0.f;

  // ---- hoisted LDS read pointers ----
  // A: row = wr2*32+l31; kk0 hi = chunk lh, kk1 hi = chunk 2|lh, lo = chunk |4; byte = ((c^(row&7))<<4)
  const int arow = wr2 * 32 + l31;
  const uint32_t aswz = (uint32_t)(arow & 7);
  const uint32_t aBase = (uint32_t)(arow * 128);
  const char* pAh0 = lds + (aBase + ((( (uint32_t)lh      ) ^ aswz) << 4));
  const char* pAh1 = lds + (aBase + (((2u | (uint32_t)lh  ) ^ aswz) << 4));
  const char* pAl0 = lds + (aBase + (((4u | (uint32_t)lh  ) ^ aswz) << 4));
  const char* pAl1 = lds + (aBase + (((6u | (uint32_t)lh  ) ^ aswz) << 4));

  // B: col = wc2*32+l31; same chunk math; region base LDS_B0, buf/gate via imm offsets
  const int bcol = wc2 * 32 + l31;
  const uint32_t bswz = (uint32_t)(bcol & 7);
  const uint32_t bBase = (uint32_t)(LDS_B0 + bcol * 128);
  const char* pBh0 = lds + (bBase + ((( (uint32_t)lh      ) ^ bswz) << 4));
  const char* pBh1 = lds + (bBase + (((2u | (uint32_t)lh  ) ^ bswz) << 4));
  const char* pBl0 = lds + (bBase + (((4u | (uint32_t)lh  ) ^ bswz) << 4));
  const char* pBl1 = lds + (bBase + (((6u | (uint32_t)lh  ) ^ bswz) << 4));

  // ---- hoisted A staging-write pointers ----
  const uint32_t wOffH = (uint32_t)(rowA * 128) + (uint32_t)(((ca ^ (rowA & 7))) << 4);
  const uint32_t wOffL = (uint32_t)(rowA * 128) + (uint32_t)((((ca | 4) ^ (rowA & 7))) << 4);
  char* wAh = lds + wOffH;   // + imm (0 or 16384)
  char* wAl = lds + wOffL;

  auto aPtr = [&](int s) -> const float* {
    if (s < 8) return inputs + (size_t)(b0 + rowA) * 256 + s * 32 + ca * 8;
    const int ss = s - 8;
    const int kc = ss >> 3;
    const int m0 = (ss & 7) * 32;
    return children + ((size_t)kc * NB + (size_t)(b0 + rowA)) * 512 + m0 + ca * 8;
  };

  auto stageB = [&](int s, int bufoff) {   // 3 glds per wave, 24 KB total
    #pragma unroll
    for (int j = 0; j < 3; ++j) {
      const int idx  = wid + j * 8;
      const int gate = idx >> 3;
      const int off  = (idx & 7) * 1024;
      glds16(wsB + (size_t)s * 98304 + (size_t)gate * 32768 + (size_t)n0 * 128 + off + lane * 16,
             lds + bufoff + gate * 8192 + off + lane * 16);
    }
  };

  f32x4 rx, ry;   // A pipeline registers

  // fp32 -> (hi,lo) bf16 split; AWR is a compile-time byte offset (0 or 16384)
#define WRITEA(AWR, X, Y)                                                     \
  { Frag8 H_, L_;                                                             \
    _Pragma("unroll")                                                         \
    for (int j = 0; j < 4; ++j) {                                             \
      __bf16 h0 = (__bf16)(X)[j];                                             \
      H_.v[j] = h0; L_.v[j] = (__bf16)((X)[j] - (float)h0);                   \
      __bf16 h1 = (__bf16)(Y)[j];                                             \
      H_.v[4 + j] = h1; L_.v[4 + j] = (__bf16)((Y)[j] - (float)h1);           \
    }                                                                         \
    *(u32x4*)(wAh + (AWR)) = H_.q;                                            \
    *(u32x4*)(wAl + (AWR)) = L_.q; }

#define DOSTEP(S, ARD, BRD, AWR, BST)                                         \
  { const int s_ = (S);                                                       \
    const bool more_ = (s_ + 1 < NSTEPS);                                     \
    if (more_) {                                                              \
      stageB(s_ + 1, BST);                                                    \
      WRITEA(AWR, rx, ry);                                                    \
    }                                                                         \
    { const int sl_ = (s_ + 2 < NSTEPS) ? s_ + 2 : NSTEPS - 1;                \
      const float* p_ = aPtr(sl_);                                            \
      rx = *(const f32x4*)p_; ry = *(const f32x4*)(p_ + 4); }                 \
    Frag8 a00, a01, a10, a11;                                                 \
    a00.q = RD(pAh0, ARD); a01.q = RD(pAh1, ARD);                             \
    a10.q = RD(pAl0, ARD); a11.q = RD(pAl1, ARD);                             \
    _Pragma("unroll")                                                         \
    for (int g = 0; g < 3; ++g) {                                             \
      Frag8 b00, b01, b10, b11;                                               \
      b00.q = RD(pBh0, (BRD) + g * 8192); b01.q = RD(pBh1, (BRD) + g * 8192); \
      b10.q = RD(pBl0, (BRD) + g * 8192); b11.q = RD(pBl1, (BRD) + g * 8192); \
      acc[g] = __builtin_amdgcn_mfma_f32_32x32x16_bf16(a00.v, b00.v, acc[g], 0, 0, 0); \
      acc[g] = __builtin_amdgcn_mfma_f32_32x32x16_bf16(a10.v, b00.v, acc[g], 0, 0, 0); \
      acc[g] = __builtin_amdgcn_mfma_f32_32x32x16_bf16(a00.v, b10.v, acc[g], 0, 0, 0); \
      acc[g] = __builtin_amdgcn_mfma_f32_32x32x16_bf16(a01.v, b01.v, acc[g], 0, 0, 0); \
      acc[g] = __builtin_amdgcn_mfma_f32_32x32x16_bf16(a11.v, b01.v, acc[g], 0, 0, 0); \
      acc[g] = __builtin_amdgcn_mfma_f32_32x32x16_bf16(a01.v, b11.v, acc[g], 0, 0, 0); \
    }                                                                         \
    /* order-proof drain (v6 semantics): counted vmcnt is unsound without */  \
    /* pinned issue order — the R8 bug */                                     \
    asm volatile("s_waitcnt vmcnt(0) lgkmcnt(0)\n\ts_barrier" ::: "memory");  \
    __builtin_amdgcn_sched_barrier(0); }

  // ---- prologue: A(0)->A0, B(0)->B0, rx=A(1) ----
  { const float* p = aPtr(0); rx = *(const f32x4*)p; ry = *(const f32x4*)(p + 4); }
  stageB(0, LDS_B0);
  WRITEA(0, rx, ry);
  { const float* p = aPtr(1); rx = *(const f32x4*)p; ry = *(const f32x4*)(p + 4); }
  asm volatile("s_waitcnt vmcnt(0) lgkmcnt(0)\n\ts_barrier" ::: "memory");
  __builtin_amdgcn_sched_barrier(0);

  #pragma unroll 1
  for (int t = 0; t < 20; ++t) {
    DOSTEP(2 * t,     0,     0,     16384, LDS_B1);   // read A0/B0, write A1, stage B1
    DOSTEP(2 * t + 1, 16384, 24576, 0,     LDS_B0);   // read A1/B1, write A0, stage B0
  }

  // ---- epilogue: 32x32 C/D mapping: col = lane&31, row = (r&3)+8*(r>>2)+4*lh ----
  {
    const int n = n0 + wc2 * 32 + l31;
    const float bin = bi[n], bon = bo[n], bun = bu[n];
    #pragma unroll
    for (int r = 0; r < 16; ++r) {
      const int row = b0 + wr2 * 32 + (r & 3) + 8 * (r >> 2) + 4 * lh;
      const float iv = acc[0][r] + bin;
      const float ov = acc[1][r] + bon;
      const float uv = acc[2][r] + bun;
      const float tu = 1.f - 2.f / (1.f + __expf(2.f * uv));
      const float si = 1.f / (1.f + __expf(-iv));
      const float cv = si * tu;
      const float so = 1.f / (1.f + __expf(-ov));
      const float tc = 1.f - 2.f / (1.f + __expf(2.f * cv));
      const float hv = so * tc;
      const size_t base = (size_t)row * 512 + (size_t)n;
      out[base]       = hv;
      out[base + 256] = cv;
    }
  }
}

// ================= v1 fallback (ws too small) =================
#define A_HI 0
#define A_LO 8192
#define B_HI 16384
#define B_LO 40960

__global__ __launch_bounds__(512, 2)
void treelstm_fused_v1(const float* __restrict__ inputs,
                       const float* __restrict__ children,
                       const float* __restrict__ Wi, const float* __restrict__ bi,
                       const float* __restrict__ Wo, const float* __restrict__ bo,
                       const float* __restrict__ Wu, const float* __restrict__ bu,
                       const float* __restrict__ Ui, const float* __restrict__ Uo,
                       const float* __restrict__ Uu,
                       float* __restrict__ out)
{
  __shared__ u32x4 lds_u4[4096];
  char* lds = (char*)lds_u4;
  const int tid = threadIdx.x;
  const int bid = blockIdx.x;
  const int wg     = (bid & 7) * 128 + (bid >> 3);
  const int strip  = wg >> 9;
  const int rowblk = wg & 511;
  const int b0 = rowblk * BM;
  const int n0 = strip * 128;
  const int rowA = tid >> 2;
  const int koff = (tid & 3) * 8;
  const float* Wg[3] = {Wi, Wo, Wu};
  const float* Ug[3] = {Ui, Uo, Uu};
  const int lane = tid & 63;
  const int wid  = tid >> 6;
  const int wr   = wid >> 2;
  const int wc   = wid & 3;
  const int lc   = lane & 15;
  const int qq   = lane >> 4;

  f32x4 acc[4][2][3];
  #pragma unroll
  for (int a = 0; a < 4; ++a)
    #pragma unroll
    for (int b = 0; b < 2; ++b)
      #pragma unroll
      for (int g = 0; g < 3; ++g)
        acc[a][b][g] = (f32x4){0.f, 0.f, 0.f, 0.f};

  float va[8];
  float vb[3][8];

  auto loadStep = [&](int s) {
    const int k0 = s * 32;
    const float* pa;
    if (s < 8) pa = inputs + (size_t)(b0 + rowA) * 256 + (k0 + koff);
    else {
      const int kc = (s - 8) >> 3;
      const int m0 = ((s - 8) & 7) * 32;
      pa = children + ((size_t)kc * NB + (size_t)(b0 + rowA)) * 512 + (m0 + koff);
    }
    f32x4 t0 = *(const f32x4*)pa;
    f32x4 t1 = *(const f32x4*)(pa + 4);
    #pragma unroll
    for (int j = 0; j < 4; ++j) { va[j] = t0[j]; va[4 + j] = t1[j]; }
    #pragma unroll
    for (int g = 0; g < 3; ++g) {
      const float* pb;
      if (s < 8) pb = Wg[g] + (size_t)(n0 + rowA) * 256 + (k0 + koff);
      else {
        const int kc = (s - 8) >> 3;
        const int m0 = ((s - 8) & 7) * 32;
        pb = Ug[g] + (size_t)kc * 65536 + (size_t)(n0 + rowA) * 256 + (m0 + koff);
      }
      f32x4 u0 = *(const f32x4*)pb;
      f32x4 u1 = *(const f32x4*)(pb + 4);
      #pragma unroll
      for (int j = 0; j < 4; ++j) { vb[g][j] = u0[j]; vb[g][4 + j] = u1[j]; }
    }
  };

  auto storeStep = [&]() {
    Frag8 h, l;
    #pragma unroll
    for (int j = 0; j < 8; ++j) {
      ushort_t hb = bf16_rne(va[j]);
      h.u[j] = hb;
      l.u[j] = bf16_rne(va[j] - bf16_f(hb));
    }
    *(u32x4*)(lds + A_HI + rowA * 64 + koff * 2) = h.q;
    *(u32x4*)(lds + A_LO + rowA * 64 + koff * 2) = l.q;
    #pragma unroll
    for (int g = 0; g < 3; ++g) {
      Frag8 hg, lg;
      #pragma unroll
      for (int j = 0; j < 8; ++j) {
        ushort_t hb = bf16_rne(vb[g][j]);
        hg.u[j] = hb;
        lg.u[j] = bf16_rne(vb[g][j] - bf16_f(hb));
      }
      *(u32x4*)(lds + B_HI + (g * 128 + rowA) * 64 + koff * 2) = hg.q;
      *(u32x4*)(lds + B_LO + (g * 128 + rowA) * 64 + koff * 2) = lg.q;
    }
  };

  auto computeStep = [&]() {
    Frag8 ah[4], al[4];
    #pragma unroll
    for (int rf = 0; rf < 4; ++rf) {
      const int row = wr * 64 + rf * 16 + lc;
      ah[rf].q = *(const u32x4*)(lds + A_HI + row * 64 + qq * 16);
      al[rf].q = *(const u32x4*)(lds + A_LO + row * 64 + qq * 16);
    }
    #pragma unroll
    for (int g = 0; g < 3; ++g) {
      #pragma unroll
      for (int cf = 0; cf < 2; ++cf) {
        const int col = wc * 32 + cf * 16 + lc;
        Frag8 bh, bl;
        bh.q = *(const u32x4*)(lds + B_HI + (g * 128 + col) * 64 + qq * 16);
        bl.q = *(const u32x4*)(lds + B_LO + (g * 128 + col) * 64 + qq * 16);
        #pragma unroll
        for (int rf = 0; rf < 4; ++rf) {
          acc[rf][cf][g] = __builtin_amdgcn_mfma_f32_16x16x32_bf16(ah[rf].v, bh.v, acc[rf][cf][g], 0, 0, 0);
          acc[rf][cf][g] = __builtin_amdgcn_mfma_f32_16x16x32_bf16(al[rf].v, bh.v, acc[rf][cf][g], 0, 0, 0);
          acc[rf][cf][g] = __builtin_amdgcn_mfma_f32_16x16x32_bf16(ah[rf].v, bl.v, acc[rf][cf][g], 0, 0, 0);
        }
      }
    }
  };

  loadStep(0);
  #pragma unroll 1
  for (int s = 0; s < NSTEPS; ++s) {
    if (s) __syncthreads();
    storeStep();
    __syncthreads();
    if (s + 1 < NSTEPS) loadStep(s + 1);
    computeStep();
  }

  #pragma unroll
  for (int cf = 0; cf < 2; ++cf) {
    const int n = n0 + wc * 32 + cf * 16 + lc;
    const float bin = bi[n], bon = bo[n], bun = bu[n];
    #pragma unroll
    for (int rf = 0; rf < 4; ++rf) {
      const int brow = b0 + wr * 64 + rf * 16 + qq * 4;
      #pragma unroll
      for (int r = 0; r < 4; ++r) {
        const float iv = acc[rf][cf][0][r] + bin;
        const float ov = acc[rf][cf][1][r] + bon;
        const float uv = acc[rf][cf][2][r] + bun;
        const float tu = 1.f - 2.f / (1.f + __expf(2.f * uv));
        const float si = 1.f / (1.f + __expf(-iv));
        const float cv = si * tu;
        const float so = 1.f / (1.f + __expf(-ov));
        const float tc = 1.f - 2.f / (1.f + __expf(2.f * cv));
        const float hv = so * tc;
        const size_t base = (size_t)(brow + r) * 512 + (size_t)n;
        out[base]       = hv;
        out[base + 256] = cv;
      }
    }
  }
}

extern "C" void kernel_launch(void* const* d_in, const int* in_sizes, int n_in,
                              void* d_out, int out_size, void* d_ws, size_t ws_size,
                              hipStream_t stream) {
  const float* inputs   = (const float*)d_in[0];
  const float* children = (const float*)d_in[1];
  const float* Wi = (const float*)d_in[3];
  const float* bi = (const float*)d_in[4];
  const float* Wo = (const float*)d_in[5];
  const float* bo = (const float*)d_in[6];
  const float* Wu = (const float*)d_in[7];
  const float* bu = (const float*)d_in[8];
  const float* Ui = (const float*)d_in[11];
  const float* Uo = (const float*)d_in[12];
  const float* Uu = (const float*)d_in[13];
  float* out = (float*)d_out;

  if (ws_size >= WS_B_BYTES) {
    char* wsB = (char*)d_ws;
    (void)hipFuncSetAttribute((const void*)treelstm_fused_v9,
                              hipFuncAttributeMaxDynamicSharedMemorySize, LDS_TOTAL);
    hipLaunchKernelGGL(prep_weights, dim3(480), dim3(256), 0, stream,
                       Wi, Wo, Wu, Ui, Uo, Uu, wsB);
    hipLaunchKernelGGL(treelstm_fused_v9, dim3(2048), dim3(512), LDS_TOTAL, stream,
                       inputs, children, wsB, bi, bo, bu, out);
  } else {
    hipLaunchKernelGGL(treelstm_fused_v1, dim3(1024), dim3(512), 0, stream,
                       inputs, children, Wi, bi, Wo, bo, Wu, bu, Ui, Uo, Uu, out);
  }
}

// Round 10
// 443.011 us; speedup vs baseline: 1.0928x; 1.0235x over previous
//
#include <hip/hip_runtime.h>
#include <stdint.h>

typedef float    f32x4  __attribute__((ext_vector_type(4)));
typedef float    f32x16 __attribute__((ext_vector_type(16)));
typedef __bf16   bf16x8 __attribute__((ext_vector_type(8)));
typedef unsigned int u32x4 __attribute__((ext_vector_type(4)));
typedef unsigned short ushort_t;

#define NB     65536
#define BM     128
#define NSTEPS 40

// ---- dynamic LDS (bytes): A dbuf 2x16K, B dbuf 2x24K = 80 KiB -> 2 blocks/CU ----
#define LDS_A0 0
#define LDS_A1 16384
#define LDS_B0 32768
#define LDS_B1 57344
#define LDS_TOTAL 81920

// ws layout: [kt 0..39][g 0..2][n 0..255][128 B row], row = swizzled hi/lo image
// chunk swizzle: c' = c ^ (r&7) ^ ((r>>3)&3)  -- the extra term kills the
// 4-way bank conflict of 32x32 fragment reads (32 consecutive rows, 1 chunk).
#define WS_B_BYTES (40ull * 3ull * 256ull * 128ull)   // 3,932,160

union Frag8 { ushort_t u[8]; u32x4 q; bf16x8 v; };

static __device__ __forceinline__ ushort_t bf16_rne(float x) {
  uint32_t u = __float_as_uint(x);
  u += 0x7FFFu + ((u >> 16) & 1u);
  return (ushort_t)(u >> 16);
}
static __device__ __forceinline__ float bf16_f(ushort_t h) {
  return __uint_as_float(((uint32_t)h) << 16);
}

typedef const __attribute__((address_space(1))) void gas_void;
typedef __attribute__((address_space(3))) void las_void;

static __device__ __forceinline__ void glds16(const void* g, void* l) {
  __builtin_amdgcn_global_load_lds((gas_void*)g, (las_void*)l, 16, 0, 0);
}

#define RD(p, off) (*(const u32x4*)((p) + (off)))
// full swizzle term for row r (3-bit result)
#define SWZ(r) ((uint32_t)((((r) & 7) ^ (((r) >> 3) & 3))))

// ============================ prep: pack weights ============================
__global__ __launch_bounds__(256)
void prep_weights(const float* __restrict__ Wi, const float* __restrict__ Wo,
                  const float* __restrict__ Wu,
                  const float* __restrict__ Ui, const float* __restrict__ Uo,
                  const float* __restrict__ Uu,
                  char* __restrict__ wsB)
{
  const int idx = blockIdx.x * 256 + threadIdx.x;   // 122880 total
  const int qq = idx & 3;
  const int n  = (idx >> 2) & 255;
  const int t  = idx >> 10;        // kt*3 + g
  const int g  = t % 3;
  const int kt = t / 3;
  const float* Wg = (g == 0) ? Wi : (g == 1) ? Wo : Wu;
  const float* Ug = (g == 0) ? Ui : (g == 1) ? Uo : Uu;
  const int k0 = kt * 32 + qq * 8;
  const float* src;
  if (k0 < 256) {
    src = Wg + (size_t)n * 256 + k0;
  } else {
    const int kc = (k0 - 256) >> 8;
    const int m  = (k0 - 256) & 255;
    src = Ug + (size_t)kc * 65536 + (size_t)n * 256 + m;
  }
  f32x4 a = *(const f32x4*)src;
  f32x4 b = *(const f32x4*)(src + 4);
  Frag8 hi, lo;
  #pragma unroll
  for (int j = 0; j < 4; ++j) {
    ushort_t h0 = bf16_rne(a[j]);
    hi.u[j] = h0; lo.u[j] = bf16_rne(a[j] - bf16_f(h0));
    ushort_t h1 = bf16_rne(b[j]);
    hi.u[4 + j] = h1; lo.u[4 + j] = bf16_rne(b[j] - bf16_f(h1));
  }
  char* base = wsB + ((size_t)t * 256 + n) * 128;
  // B tile rows are n&63 within each 64-row gate tile; (n>>3)&3 is invariant
  // to the tile base (64 | 8) so using n directly is equivalent.
  const uint32_t sw = SWZ(n & 63);
  *(u32x4*)(base + ((qq ^ sw) << 4))       = hi.q;
  *(u32x4*)(base + (((qq | 4) ^ sw) << 4)) = lo.q;
}

// ====== v10: v9 + conflict-free chunk swizzle (c ^ (r&7) ^ ((r>>3)&3)) ======
__global__ __launch_bounds__(512, 4)
void treelstm_fused_v10(const float* __restrict__ inputs,
                        const float* __restrict__ children,
                        const char*  __restrict__ wsB,
                        const float* __restrict__ bi, const float* __restrict__ bo,
                        const float* __restrict__ bu,
                        float* __restrict__ out)
{
  extern __shared__ __align__(16) char lds[];

  const int tid = threadIdx.x;
  const int bid = blockIdx.x;
  // XCD swizzle over 2048 blocks
  const int wg     = (bid & 7) * 256 + (bid >> 3);
  const int strip  = wg >> 9;      // 0..3
  const int rowblk = wg & 511;
  const int b0 = rowblk * BM;
  const int n0 = strip * 64;

  const int rowA = tid >> 2;       // 0..127  (staging row)
  const int ca   = tid & 3;        // staging k-chunk
  const int lane = tid & 63;
  const int wid  = tid >> 6;       // 0..7
  const int wr2  = wid >> 1;       // 0..3  (32-row slab)
  const int wc2  = wid & 1;        // 0..1  (32-col slab per gate)
  const int l31  = lane & 31;
  const int lh   = lane >> 5;      // k-half selector

  f32x16 acc[3];
  #pragma unroll
  for (int g = 0; g < 3; ++g)
    #pragma unroll
    for (int r = 0; r < 16; ++r)
      acc[g][r] = 0.f;

  // ---- hoisted LDS read pointers ----
  // A: row = wr2*32+l31; chunks kk0={lh}, kk1={2|lh}, lo = |4; byte = ((c^swz)<<4)
  const int arow = wr2 * 32 + l31;
  const uint32_t aswz = SWZ(arow);
  const uint32_t aBase = (uint32_t)(arow * 128);
  const char* pAh0 = lds + (aBase + ((( (uint32_t)lh      ) ^ aswz) << 4));
  const char* pAh1 = lds + (aBase + (((2u | (uint32_t)lh  ) ^ aswz) << 4));
  const char* pAl0 = lds + (aBase + (((4u | (uint32_t)lh  ) ^ aswz) << 4));
  const char* pAl1 = lds + (aBase + (((6u | (uint32_t)lh  ) ^ aswz) << 4));

  // B: col = wc2*32+l31 (row within 64-row gate tile); buf/gate via imm offsets
  const int bcol = wc2 * 32 + l31;
  const uint32_t bswz = SWZ(bcol);
  const uint32_t bBase = (uint32_t)(LDS_B0 + bcol * 128);
  const char* pBh0 = lds + (bBase + ((( (uint32_t)lh      ) ^ bswz) << 4));
  const char* pBh1 = lds + (bBase + (((2u | (uint32_t)lh  ) ^ bswz) << 4));
  const char* pBl0 = lds + (bBase + (((4u | (uint32_t)lh  ) ^ bswz) << 4));
  const char* pBl1 = lds + (bBase + (((6u | (uint32_t)lh  ) ^ bswz) << 4));

  // ---- hoisted A staging-write pointers (same swizzle family) ----
  const uint32_t wswz = SWZ(rowA);
  const uint32_t wOffH = (uint32_t)(rowA * 128) + ((((uint32_t)ca      ) ^ wswz) << 4);
  const uint32_t wOffL = (uint32_t)(rowA * 128) + ((((uint32_t)ca | 4u ) ^ wswz) << 4);
  char* wAh = lds + wOffH;   // + imm (0 or 16384)
  char* wAl = lds + wOffL;

  auto aPtr = [&](int s) -> const float* {
    if (s < 8) return inputs + (size_t)(b0 + rowA) * 256 + s * 32 + ca * 8;
    const int ss = s - 8;
    const int kc = ss >> 3;
    const int m0 = (ss & 7) * 32;
    return children + ((size_t)kc * NB + (size_t)(b0 + rowA)) * 512 + m0 + ca * 8;
  };

  auto stageB = [&](int s, int bufoff) {   // 3 glds per wave, 24 KB total
    #pragma unroll
    for (int j = 0; j < 3; ++j) {
      const int idx  = wid + j * 8;
      const int gate = idx >> 3;
      const int off  = (idx & 7) * 1024;
      glds16(wsB + (size_t)s * 98304 + (size_t)gate * 32768 + (size_t)n0 * 128 + off + lane * 16,
             lds + bufoff + gate * 8192 + off + lane * 16);
    }
  };

  f32x4 rx, ry;   // A pipeline registers

  // fp32 -> (hi,lo) bf16 split; AWR is a compile-time byte offset (0 or 16384)
#define WRITEA(AWR, X, Y)                                                     \
  { Frag8 H_, L_;                                                             \
    _Pragma("unroll")                                                         \
    for (int j = 0; j < 4; ++j) {                                             \
      __bf16 h0 = (__bf16)(X)[j];                                             \
      H_.v[j] = h0; L_.v[j] = (__bf16)((X)[j] - (float)h0);                   \
      __bf16 h1 = (__bf16)(Y)[j];                                             \
      H_.v[4 + j] = h1; L_.v[4 + j] = (__bf16)((Y)[j] - (float)h1);           \
    }                                                                         \
    *(u32x4*)(wAh + (AWR)) = H_.q;                                            \
    *(u32x4*)(wAl + (AWR)) = L_.q; }

#define DOSTEP(S, ARD, BRD, AWR, BST)                                         \
  { const int s_ = (S);                                                       \
    const bool more_ = (s_ + 1 < NSTEPS);                                     \
    if (more_) {                                                              \
      stageB(s_ + 1, BST);                                                    \
      WRITEA(AWR, rx, ry);                                                    \
    }                                                                         \
    { const int sl_ = (s_ + 2 < NSTEPS) ? s_ + 2 : NSTEPS - 1;                \
      const float* p_ = aPtr(sl_);                                            \
      rx = *(const f32x4*)p_; ry = *(const f32x4*)(p_ + 4); }                 \
    Frag8 a00, a01, a10, a11;                                                 \
    a00.q = RD(pAh0, ARD); a01.q = RD(pAh1, ARD);                             \
    a10.q = RD(pAl0, ARD); a11.q = RD(pAl1, ARD);                             \
    _Pragma("unroll")                                                         \
    for (int g = 0; g < 3; ++g) {                                             \
      Frag8 b00, b01, b10, b11;                                               \
      b00.q = RD(pBh0, (BRD) + g * 8192); b01.q = RD(pBh1, (BRD) + g * 8192); \
      b10.q = RD(pBl0, (BRD) + g * 8192); b11.q = RD(pBl1, (BRD) + g * 8192); \
      acc[g] = __builtin_amdgcn_mfma_f32_32x32x16_bf16(a00.v, b00.v, acc[g], 0, 0, 0); \
      acc[g] = __builtin_amdgcn_mfma_f32_32x32x16_bf16(a10.v, b00.v, acc[g], 0, 0, 0); \
      acc[g] = __builtin_amdgcn_mfma_f32_32x32x16_bf16(a00.v, b10.v, acc[g], 0, 0, 0); \
      acc[g] = __builtin_amdgcn_mfma_f32_32x32x16_bf16(a01.v, b01.v, acc[g], 0, 0, 0); \
      acc[g] = __builtin_amdgcn_mfma_f32_32x32x16_bf16(a11.v, b01.v, acc[g], 0, 0, 0); \
      acc[g] = __builtin_amdgcn_mfma_f32_32x32x16_bf16(a01.v, b11.v, acc[g], 0, 0, 0); \
    }                                                                         \
    /* order-proof drain: counted vmcnt unsound without pinned issue order */ \
    asm volatile("s_waitcnt vmcnt(0) lgkmcnt(0)\n\ts_barrier" ::: "memory");  \
    __builtin_amdgcn_sched_barrier(0); }

  // ---- prologue: A(0)->A0, B(0)->B0, rx=A(1) ----
  { const float* p = aPtr(0); rx = *(const f32x4*)p; ry = *(const f32x4*)(p + 4); }
  stageB(0, LDS_B0);
  WRITEA(0, rx, ry);
  { const float* p = aPtr(1); rx = *(const f32x4*)p; ry = *(const f32x4*)(p + 4); }
  asm volatile("s_waitcnt vmcnt(0) lgkmcnt(0)\n\ts_barrier" ::: "memory");
  __builtin_amdgcn_sched_barrier(0);

  #pragma unroll 1
  for (int t = 0; t < 20; ++t) {
    DOSTEP(2 * t,     0,     0,     16384, LDS_B1);   // read A0/B0, write A1, stage B1
    DOSTEP(2 * t + 1, 16384, 24576, 0,     LDS_B0);   // read A1/B1, write A0, stage B0
  }

  // ---- epilogue: 32x32 C/D mapping: col = lane&31, row = (r&3)+8*(r>>2)+4*lh ----
  {
    const int n = n0 + wc2 * 32 + l31;
    const float bin = bi[n], bon = bo[n], bun = bu[n];
    #pragma unroll
    for (int r = 0; r < 16; ++r) {
      const int row = b0 + wr2 * 32 + (r & 3) + 8 * (r >> 2) + 4 * lh;
      const float iv = acc[0][r] + bin;
      const float ov = acc[1][r] + bon;
      const float uv = acc[2][r] + bun;
      const float tu = 1.f - 2.f / (1.f + __expf(2.f * uv));
      const float si = 1.f / (1.f + __expf(-iv));
      const float cv = si * tu;
      const float so = 1.f / (1.f + __expf(-ov));
      const float tc = 1.f - 2.f / (1.f + __expf(2.f * cv));
      const float hv = so * tc;
      const size_t base = (size_t)row * 512 + (size_t)n;
      out[base]       = hv;
      out[base + 256] = cv;
    }
  }
}

// ================= v1 fallback (ws too small) =================
#define A_HI 0
#define A_LO 8192
#define B_HI 16384
#define B_LO 40960

__global__ __launch_bounds__(512, 2)
void treelstm_fused_v1(const float* __restrict__ inputs,
                       const float* __restrict__ children,
                       const float* __restrict__ Wi, const float* __restrict__ bi,
                       const float* __restrict__ Wo, const float* __restrict__ bo,
                       const float* __restrict__ Wu, const float* __restrict__ bu,
                       const float* __restrict__ Ui, const float* __restrict__ Uo,
                       const float* __restrict__ Uu,
                       float* __restrict__ out)
{
  __shared__ u32x4 lds_u4[4096];
  char* lds = (char*)lds_u4;
  const int tid = threadIdx.x;
  const int bid = blockIdx.x;
  const int wg     = (bid & 7) * 128 + (bid >> 3);
  const int strip  = wg >> 9;
  const int rowblk = wg & 511;
  const int b0 = rowblk * BM;
  const int n0 = strip * 128;
  const int rowA = tid >> 2;
  const int koff = (tid & 3) * 8;
  const float* Wg[3] = {Wi, Wo, Wu};
  const float* Ug[3] = {Ui, Uo, Uu};
  const int lane = tid & 63;
  const int wid  = tid >> 6;
  const int wr   = wid >> 2;
  const int wc   = wid & 3;
  const int lc   = lane & 15;
  const int qq   = lane >> 4;

  f32x4 acc[4][2][3];
  #pragma unroll
  for (int a = 0; a < 4; ++a)
    #pragma unroll
    for (int b = 0; b < 2; ++b)
      #pragma unroll
      for (int g = 0; g < 3; ++g)
        acc[a][b][g] = (f32x4){0.f, 0.f, 0.f, 0.f};

  float va[8];
  float vb[3][8];

  auto loadStep = [&](int s) {
    const int k0 = s * 32;
    const float* pa;
    if (s < 8) pa = inputs + (size_t)(b0 + rowA) * 256 + (k0 + koff);
    else {
      const int kc = (s - 8) >> 3;
      const int m0 = ((s - 8) & 7) * 32;
      pa = children + ((size_t)kc * NB + (size_t)(b0 + rowA)) * 512 + (m0 + koff);
    }
    f32x4 t0 = *(const f32x4*)pa;
    f32x4 t1 = *(const f32x4*)(pa + 4);
    #pragma unroll
    for (int j = 0; j < 4; ++j) { va[j] = t0[j]; va[4 + j] = t1[j]; }
    #pragma unroll
    for (int g = 0; g < 3; ++g) {
      const float* pb;
      if (s < 8) pb = Wg[g] + (size_t)(n0 + rowA) * 256 + (k0 + koff);
      else {
        const int kc = (s - 8) >> 3;
        const int m0 = ((s - 8) & 7) * 32;
        pb = Ug[g] + (size_t)kc * 65536 + (size_t)(n0 + rowA) * 256 + (m0 + koff);
      }
      f32x4 u0 = *(const f32x4*)pb;
      f32x4 u1 = *(const f32x4*)(pb + 4);
      #pragma unroll
      for (int j = 0; j < 4; ++j) { vb[g][j] = u0[j]; vb[g][4 + j] = u1[j]; }
    }
  };

  auto storeStep = [&]() {
    Frag8 h, l;
    #pragma unroll
    for (int j = 0; j < 8; ++j) {
      ushort_t hb = bf16_rne(va[j]);
      h.u[j] = hb;
      l.u[j] = bf16_rne(va[j] - bf16_f(hb));
    }
    *(u32x4*)(lds + A_HI + rowA * 64 + koff * 2) = h.q;
    *(u32x4*)(lds + A_LO + rowA * 64 + koff * 2) = l.q;
    #pragma unroll
    for (int g = 0; g < 3; ++g) {
      Frag8 hg, lg;
      #pragma unroll
      for (int j = 0; j < 8; ++j) {
        ushort_t hb = bf16_rne(vb[g][j]);
        hg.u[j] = hb;
        lg.u[j] = bf16_rne(vb[g][j] - bf16_f(hb));
      }
      *(u32x4*)(lds + B_HI + (g * 128 + rowA) * 64 + koff * 2) = hg.q;
      *(u32x4*)(lds + B_LO + (g * 128 + rowA) * 64 + koff * 2) = lg.q;
    }
  };

  auto computeStep = [&]() {
    Frag8 ah[4], al[4];
    #pragma unroll
    for (int rf = 0; rf < 4; ++rf) {
      const int row = wr * 64 + rf * 16 + lc;
      ah[rf].q = *(const u32x4*)(lds + A_HI + row * 64 + qq * 16);
      al[rf].q = *(const u32x4*)(lds + A_LO + row * 64 + qq * 16);
    }
    #pragma unroll
    for (int g = 0; g < 3; ++g) {
      #pragma unroll
      for (int cf = 0; cf < 2; ++cf) {
        const int col = wc * 32 + cf * 16 + lc;
        Frag8 bh, bl;
        bh.q = *(const u32x4*)(lds + B_HI + (g * 128 + col) * 64 + qq * 16);
        bl.q = *(const u32x4*)(lds + B_LO + (g * 128 + col) * 64 + qq * 16);
        #pragma unroll
        for (int rf = 0; rf < 4; ++rf) {
          acc[rf][cf][g] = __builtin_amdgcn_mfma_f32_16x16x32_bf16(ah[rf].v, bh.v, acc[rf][cf][g], 0, 0, 0);
          acc[rf][cf][g] = __builtin_amdgcn_mfma_f32_16x16x32_bf16(al[rf].v, bh.v, acc[rf][cf][g], 0, 0, 0);
          acc[rf][cf][g] = __builtin_amdgcn_mfma_f32_16x16x32_bf16(ah[rf].v, bl.v, acc[rf][cf][g], 0, 0, 0);
        }
      }
    }
  };

  loadStep(0);
  #pragma unroll 1
  for (int s = 0; s < NSTEPS; ++s) {
    if (s) __syncthreads();
    storeStep();
    __syncthreads();
    if (s + 1 < NSTEPS) loadStep(s + 1);
    computeStep();
  }

  #pragma unroll
  for (int cf = 0; cf < 2; ++cf) {
    const int n = n0 + wc * 32 + cf * 16 + lc;
    const float bin = bi[n], bon = bo[n], bun = bu[n];
    #pragma unroll
    for (int rf = 0; rf < 4; ++rf) {
      const int brow = b0 + wr * 64 + rf * 16 + qq * 4;
      #pragma unroll
      for (int r = 0; r < 4; ++r) {
        const float iv = acc[rf][cf][0][r] + bin;
        const float ov = acc[rf][cf][1][r] + bon;
        const float uv = acc[rf][cf][2][r] + bun;
        const float tu = 1.f - 2.f / (1.f + __expf(2.f * uv));
        const float si = 1.f / (1.f + __expf(-iv));
        const float cv = si * tu;
        const float so = 1.f / (1.f + __expf(-ov));
        const float tc = 1.f - 2.f / (1.f + __expf(2.f * cv));
        const float hv = so * tc;
        const size_t base = (size_t)(brow + r) * 512 + (size_t)n;
        out[base]       = hv;
        out[base + 256] = cv;
      }
    }
  }
}

extern "C" void kernel_launch(void* const* d_in, const int* in_sizes, int n_in,
                              void* d_out, int out_size, void* d_ws, size_t ws_size,
                              hipStream_t stream) {
  const float* inputs   = (const float*)d_in[0];
  const float* children = (const float*)d_in[1];
  const float* Wi = (const float*)d_in[3];
  const float* bi = (const float*)d_in[4];
  const float* Wo = (const float*)d_in[5];
  const float* bo = (const float*)d_in[6];
  const float* Wu = (const float*)d_in[7];
  const float* bu = (const float*)d_in[8];
  const float* Ui = (const float*)d_in[11];
  const float* Uo = (const float*)d_in[12];
  const float* Uu = (const float*)d_in[13];
  float* out = (float*)d_out;

  if (ws_size >= WS_B_BYTES) {
    char* wsB = (char*)d_ws;
    (void)hipFuncSetAttribute((const void*)treelstm_fused_v10,
                              hipFuncAttributeMaxDynamicSharedMemorySize, LDS_TOTAL);
    hipLaunchKernelGGL(prep_weights, dim3(480), dim3(256), 0, stream,
                       Wi, Wo, Wu, Ui, Uo, Uu, wsB);
    hipLaunchKernelGGL(treelstm_fused_v10, dim3(2048), dim3(512), LDS_TOTAL, stream,
                       inputs, children, wsB, bi, bo, bu, out);
  } else {
    hipLaunchKernelGGL(treelstm_fused_v1, dim3(1024), dim3(512), 0, stream,
                       inputs, children, Wi, bi, Wo, bo, Wu, bu, Ui, Uo, Uu, out);
  }
}